// Round 1
// baseline (193.885 us; speedup 1.0000x reference)
//
#include <hip/hip_runtime.h>

constexpr int S  = 256;
constexpr int NL = 17;
constexpr int L  = 19;   // start = 17, end = 18

// One wave (64 threads) per block; each half-wave (32 lanes) owns one sequence.
// Lane i (0..18) owns state i. Probability-domain forward recursion with
// per-4-step max renormalization; gold path score fused into the same loop.
__global__ __launch_bounds__(64)
void crf_fwd(const float* __restrict__ logits,
             const int*   __restrict__ labels,
             const int*   __restrict__ lens,
             const float* __restrict__ transition,
             float* __restrict__ out)
{
    __shared__ float Tsh[L * L];
    __shared__ __align__(16) float pbuf[2][20];

    const int tid  = threadIdx.x;
    const int half = tid >> 5;
    const int lane = tid & 31;
    const int b    = (blockIdx.x << 1) + half;

    for (int k = tid; k < L * L; k += 64) Tsh[k] = transition[k];
    if (lane == L) pbuf[half][L] = 0.0f;   // pad slot [19] stays 0 forever
    __syncthreads();

    const int  i      = lane;
    const bool active = (i < L);
    const int  ic     = active ? i : 0;

    // E row for my destination state: E[i][j] = exp(T[i][j]) (T is [to][from])
    float Erow[L];
    #pragma unroll
    for (int j = 0; j < L; ++j) Erow[j] = __expf(Tsh[ic * L + j]);

    const int len = lens[b];
    int mlv = max(len, __shfl_xor(len, 32));
    const int maxlen = __builtin_amdgcn_readfirstlane(mlv);

    const float* lgp  = logits + (size_t)b * S * NL;
    const int*   labp = labels + (size_t)b * S;

    float p = (i == L - 2) ? 1.0f : 0.0f;   // alpha0 = e_start
    float m = 0.0f;
    float gsum = 0.0f;
    int prevlab = L - 2;                    // start

    // software pipeline, depth 2
    float lgA = 0.0f, lgB = 0.0f;
    if (i < NL) lgA = lgp[i];
    int labA = labp[0];
    if (i < NL) lgB = lgp[NL + i];
    int labB = labp[1];

    for (int t = 0; t < maxlen; ++t) {
        const float lg  = lgA;
        const int   lab = labA;
        lgA = lgB; labA = labB;
        const int tn = (t + 2 < S) ? (t + 2) : (S - 1);
        if (i < NL) lgB = lgp[tn * NL + i];
        labB = labp[tn];

        const bool upd = (t < len);

        // ---- gold score (fused): unary + transition chain ----
        if (upd) {
            if (i == lab) {
                float g = lg + Tsh[lab * L + prevlab];
                if (t == len - 1) g += Tsh[(L - 1) * L + lab];  // T[end, last]
                gsum += g;
            }
            prevlab = lab;
        }

        const float el = (i < NL) ? __expf(lg) : 0.0f;

        // ---- broadcast p through LDS ----
        if (active) pbuf[half][i] = p;
        __syncthreads();
        const float4* q = (const float4*)(&pbuf[half][0]);
        const float4 q0 = q[0], q1 = q[1], q2 = q[2], q3 = q[3], q4 = q[4];

        // v = sum_j p[j] * E[i][j], 4 independent accumulator chains
        float a0 = q0.x * Erow[0];
        float a1 = q0.y * Erow[1];
        float a2 = q0.z * Erow[2];
        float a3 = q0.w * Erow[3];
        a0 = fmaf(q1.x, Erow[4],  a0);
        a1 = fmaf(q1.y, Erow[5],  a1);
        a2 = fmaf(q1.z, Erow[6],  a2);
        a3 = fmaf(q1.w, Erow[7],  a3);
        a0 = fmaf(q2.x, Erow[8],  a0);
        a1 = fmaf(q2.y, Erow[9],  a1);
        a2 = fmaf(q2.z, Erow[10], a2);
        a3 = fmaf(q2.w, Erow[11], a3);
        a0 = fmaf(q3.x, Erow[12], a0);
        a1 = fmaf(q3.y, Erow[13], a1);
        a2 = fmaf(q3.z, Erow[14], a2);
        a3 = fmaf(q3.w, Erow[15], a3);
        a0 = fmaf(q4.x, Erow[16], a0);
        a1 = fmaf(q4.y, Erow[17], a1);
        a2 = fmaf(q4.z, Erow[18], a2);

        float v  = (a0 + a1) + (a2 + a3);
        float pn = v * el;

        // renormalize every 4 steps (fp32 range >> 4 steps of growth)
        if ((t & 3) == 3) {
            float m0 = fmaxf(fmaxf(q0.x, q0.y), fmaxf(q0.z, q0.w));
            float m1 = fmaxf(fmaxf(q1.x, q1.y), fmaxf(q1.z, q1.w));
            float m2 = fmaxf(fmaxf(q2.x, q2.y), fmaxf(q2.z, q2.w));
            float m3 = fmaxf(fmaxf(q3.x, q3.y), fmaxf(q3.z, q3.w));
            float m4 = fmaxf(fmaxf(q4.x, q4.y), q4.z);
            float mx = fmaxf(fmaxf(m0, m1), fmaxf(fmaxf(m2, m3), m4));
            pn *= __frcp_rn(mx);
            if (upd) m += __logf(mx);
        }
        p = upd ? pn : p;
    }

    // ---- epilogue: alpha += T[end,:], norm = m + log(sum_i p_i * exp(T[end,i])) ----
    const float Eend = __expf(Tsh[(L - 1) * L + ic]);
    float term = active ? p * Eend : 0.0f;
    if (active) pbuf[half][i] = term;
    __syncthreads();
    const float4* qf = (const float4*)(&pbuf[half][0]);
    const float4 f0 = qf[0], f1 = qf[1], f2 = qf[2], f3 = qf[3], f4 = qf[4];
    float s0 = (f0.x + f0.y) + (f0.z + f0.w);
    float s1 = (f1.x + f1.y) + (f1.z + f1.w);
    float s2 = (f2.x + f2.y) + (f2.z + f2.w);
    float s3 = (f3.x + f3.y) + (f3.z + f3.w);
    float s4 = (f4.x + f4.y) + f4.z;
    float ssum = ((s0 + s1) + (s2 + s3)) + s4;
    float norm = m + __logf(ssum);

    // reduce gold over the half-wave
    #pragma unroll
    for (int off = 16; off >= 1; off >>= 1)
        gsum += __shfl_xor(gsum, off, 32);

    if (lane == 0) out[b] = gsum - norm;
}

extern "C" void kernel_launch(void* const* d_in, const int* in_sizes, int n_in,
                              void* d_out, int out_size, void* d_ws, size_t ws_size,
                              hipStream_t stream)
{
    (void)n_in; (void)out_size; (void)d_ws; (void)ws_size;
    const float* logits     = (const float*)d_in[0];
    const int*   labels     = (const int*)d_in[1];
    const int*   lens       = (const int*)d_in[2];
    const float* transition = (const float*)d_in[3];
    float*       out        = (float*)d_out;
    const int B = in_sizes[2];
    crf_fwd<<<dim3(B / 2), dim3(64), 0, stream>>>(logits, labels, lens, transition, out);
}

// Round 2
// 148.978 us; speedup vs baseline: 1.3014x; 1.3014x over previous
//
#include <hip/hip_runtime.h>

constexpr int S  = 256;
constexpr int NL = 17;
constexpr int L  = 19;   // start = 17, end = 18

// One wave (64 threads) per block; each half-wave (32 lanes) owns one sequence.
// Lane i (0..18) owns destination state i. Probability-domain forward recursion,
// per-4-step max renormalization. No __syncthreads in the loop: single-wave
// block, LDS ordering via lgkmcnt-only fence so global prefetches stay in
// flight (depth-8 register pipeline).
__global__ __launch_bounds__(64)
void crf_fwd(const float* __restrict__ logits,
             const int*   __restrict__ labels,
             const int*   __restrict__ lens,
             const float* __restrict__ transition,
             float* __restrict__ out)
{
    __shared__ float Tsh[L * L];
    // pbuf[half][parity][20 floats] ; 80 B stride keeps float4 alignment
    __shared__ __align__(16) float pbuf[2][2][20];

    const int tid  = threadIdx.x;
    const int half = tid >> 5;
    const int lane = tid & 31;
    const int b    = (blockIdx.x << 1) + half;

    for (int k = tid; k < L * L; k += 64) Tsh[k] = transition[k];
    __syncthreads();   // once, outside the loop: Tsh visible to both halves

    const int  i   = lane;
    const bool act = (i < L);
    const int  ic  = act ? i : 0;

    // E row for my destination state: E[i][j] = exp(T[i][j]) (T is [to][from])
    float Erow[L];
    #pragma unroll
    for (int j = 0; j < L; ++j) Erow[j] = __expf(Tsh[ic * L + j]);

    const int len = lens[b];
    int mlv = max(len, __shfl_xor(len, 32));
    const int maxlen  = __builtin_amdgcn_readfirstlane(mlv);
    const int maxlen8 = (maxlen + 7) & ~7;

    const float* lgp  = logits + (size_t)b * S * NL;
    const int*   labp = labels + (size_t)b * S;

    float p = (i == L - 2) ? 1.0f : 0.0f;   // alpha0 = e_start
    float m    = 0.0f;   // log-scale offset (uniform per half)
    float utot = 0.0f;   // per-lane unary partial
    float btot = 0.0f;   // uniform binary partial
    int prevlab = L - 2; // start

    // depth-8 register pipeline
    float lgbuf[8];
    int   labbuf[8];
    #pragma unroll
    for (int u = 0; u < 8; ++u) {
        lgbuf[u]  = (i < NL) ? lgp[u * NL + i] : 0.0f;
        labbuf[u] = labp[u];
    }

    for (int tb = 0; tb < maxlen8; tb += 8) {
        #pragma unroll
        for (int u = 0; u < 8; ++u) {
            const int   t   = tb + u;
            const float lg  = lgbuf[u];
            const int   lab = labbuf[u];
            const int   tn  = (t + 8 < S) ? (t + 8) : (S - 1);
            lgbuf[u]  = (i < NL) ? lgp[tn * NL + i] : 0.0f;
            labbuf[u] = labp[tn];

            const bool upd = (t < len);

            // ---- gold score, no shuffles ----
            // unary: only the lane matching the label takes its logit
            utot += (upd && i == lab) ? lg : 0.0f;
            // binary: uniform broadcast read of T[lab, prevlab]
            const float gtr = Tsh[lab * L + prevlab];
            btot += upd ? gtr : 0.0f;
            prevlab = upd ? lab : prevlab;

            const float el = (i < NL) ? __expf(lg) : 0.0f;

            // ---- broadcast p through LDS (parity double-buffer) ----
            float* pb = &pbuf[half][u & 1][0];
            if (act) pb[i] = p;
            // order ds_write before ds_read; do NOT drain vmcnt (prefetch!)
            asm volatile("s_waitcnt lgkmcnt(0)" ::: "memory");
            const float4* q = (const float4*)pb;
            const float4 q0 = q[0], q1 = q[1], q2 = q[2], q3 = q[3], q4 = q[4];

            // v = sum_j p[j] * E[i][j], 4 independent accumulator chains
            float a0 = q0.x * Erow[0];
            float a1 = q0.y * Erow[1];
            float a2 = q0.z * Erow[2];
            float a3 = q0.w * Erow[3];
            a0 = fmaf(q1.x, Erow[4],  a0);
            a1 = fmaf(q1.y, Erow[5],  a1);
            a2 = fmaf(q1.z, Erow[6],  a2);
            a3 = fmaf(q1.w, Erow[7],  a3);
            a0 = fmaf(q2.x, Erow[8],  a0);
            a1 = fmaf(q2.y, Erow[9],  a1);
            a2 = fmaf(q2.z, Erow[10], a2);
            a3 = fmaf(q2.w, Erow[11], a3);
            a0 = fmaf(q3.x, Erow[12], a0);
            a1 = fmaf(q3.y, Erow[13], a1);
            a2 = fmaf(q3.z, Erow[14], a2);
            a3 = fmaf(q3.w, Erow[15], a3);
            a0 = fmaf(q4.x, Erow[16], a0);
            a1 = fmaf(q4.y, Erow[17], a1);
            a2 = fmaf(q4.z, Erow[18], a2);

            float v  = (a0 + a1) + (a2 + a3);
            float pn = v * el;

            // renormalize every 4 steps (fp32 range >> 4 steps of growth)
            if ((t & 3) == 3) {
                float m0 = fmaxf(fmaxf(q0.x, q0.y), fmaxf(q0.z, q0.w));
                float m1 = fmaxf(fmaxf(q1.x, q1.y), fmaxf(q1.z, q1.w));
                float m2 = fmaxf(fmaxf(q2.x, q2.y), fmaxf(q2.z, q2.w));
                float m3 = fmaxf(fmaxf(q3.x, q3.y), fmaxf(q3.z, q3.w));
                float m4 = fmaxf(fmaxf(q4.x, q4.y), q4.z);
                float mx = fmaxf(fmaxf(m0, m1), fmaxf(fmaxf(m2, m3), m4));
                pn *= __frcp_rn(mx);
                if (upd) m += __logf(mx);
            }
            p = upd ? pn : p;
        }
    }

    // ---- epilogue ----
    // norm = m + log(sum_i p_i * exp(T[end,i]))
    const float Eend = __expf(Tsh[(L - 1) * L + ic]);
    float term = act ? p * Eend : 0.0f;
    #pragma unroll
    for (int off = 16; off >= 1; off >>= 1)
        term += __shfl_xor(term, off, 32);
    const float norm = m + __logf(term);

    // gold = sum(unary) + binary + T[end, last_label]
    #pragma unroll
    for (int off = 16; off >= 1; off >>= 1)
        utot += __shfl_xor(utot, off, 32);
    const int lastlab = labp[len - 1];
    const float gold = utot + btot + Tsh[(L - 1) * L + lastlab];

    if (lane == 0) out[b] = gold - norm;
}

extern "C" void kernel_launch(void* const* d_in, const int* in_sizes, int n_in,
                              void* d_out, int out_size, void* d_ws, size_t ws_size,
                              hipStream_t stream)
{
    (void)n_in; (void)out_size; (void)d_ws; (void)ws_size;
    const float* logits     = (const float*)d_in[0];
    const int*   labels     = (const int*)d_in[1];
    const int*   lens       = (const int*)d_in[2];
    const float* transition = (const float*)d_in[3];
    float*       out        = (float*)d_out;
    const int B = in_sizes[2];
    crf_fwd<<<dim3(B / 2), dim3(64), 0, stream>>>(logits, labels, lens, transition, out);
}

// Round 3
// 140.371 us; speedup vs baseline: 1.3812x; 1.0613x over previous
//
#include <hip/hip_runtime.h>

constexpr int S  = 256;
constexpr int NL = 17;
constexpr int L  = 19;   // start = 17, end = 18
constexpr int WPB = 2;   // waves per block

// One wave per sequence. Half-wave 0: forward recursion over tokens [0,mid).
// Half-wave 1: backward recursion over tokens [mid,len), starting from
// B_len = E[end,:]. Combine: P = sum_j A_mid[j] * B_mid[j].
// Probability domain, per-4-step renorm, lgkmcnt-only fences (no vmcnt drain),
// depth-8 register prefetch pipeline.
__global__ __launch_bounds__(64 * WPB)
void crf_fwd(const float* __restrict__ logits,
             const int*   __restrict__ labels,
             const int*   __restrict__ lens,
             const float* __restrict__ transition,
             float* __restrict__ out)
{
    __shared__ float Tsh[L * L];
    __shared__ __align__(16) float pbuf[WPB][2][2][20];  // [wave][half][parity]

    const int tid  = threadIdx.x;
    const int wave = tid >> 6;
    const int wtid = tid & 63;
    const int half = wtid >> 5;   // 0 = fwd, 1 = bwd
    const int lane = wtid & 31;
    const int b    = blockIdx.x * WPB + wave;

    for (int k = tid; k < L * L; k += 64 * WPB) Tsh[k] = transition[k];
    __syncthreads();   // once; after this only wave-local fences

    const int  i   = lane;
    const bool act = (i < L);
    const int  ic  = act ? i : 0;

    // coef[j]: fwd lane i needs row i of E; bwd lane i needs column i of E.
    float coef[L];
    #pragma unroll
    for (int j = 0; j < L; ++j)
        coef[j] = __expf(half ? Tsh[j * L + ic] : Tsh[ic * L + j]);

    const int len = lens[b];
    const int mid = len >> 1;
    const int nf  = mid;          // fwd step count
    const int nb  = len - mid;    // bwd step count (>= nf)
    const int nup = half ? nb : nf;
    const int nsteps8 = (nb + 7) & ~7;

    const float* lgp  = logits + (size_t)b * S * NL;
    const int*   labp = labels + (size_t)b * S;

    // initial vector: fwd A_0 = e_start ; bwd B_len[j] = E[end,j]
    float p = half ? (act ? __expf(Tsh[(L - 1) * L + ic]) : 0.0f)
                   : ((i == L - 2) ? 1.0f : 0.0f);
    float m    = 0.0f;   // log-scale offset (uniform per half)
    float utot = 0.0f;   // per-lane unary partial
    float btot = 0.0f;   // uniform binary partial
    int   prevF = L - 2; // fwd transition chain state (start)

    if (half) btot = Tsh[(L - 1) * L + labp[len - 1]];  // T[end, last]

    // depth-8 prefetch pipeline (fwd walks up from 0, bwd walks down from len-1)
    float lgbuf[8];
    int   labbuf[8];
    #pragma unroll
    for (int u = 0; u < 8; ++u) {
        int tb0 = len - 1 - u; tb0 = (tb0 > 0) ? tb0 : 0;
        const int tok = half ? tb0 : u;
        lgbuf[u]  = (i < NL) ? lgp[tok * NL + i] : 0.0f;
        labbuf[u] = labp[tok];
    }

    for (int tb = 0; tb < nsteps8; tb += 8) {
        #pragma unroll
        for (int u = 0; u < 8; ++u) {
            const int   t   = tb + u;
            const float lg  = lgbuf[u];
            const int   lab = labbuf[u];
            // for bwd, the NEXT iteration's label is token (utok-1): the prev label
            const int   labnxt = labbuf[(u + 1) & 7];
            {
                int tpf = t + 8;       tpf = (tpf < S) ? tpf : (S - 1);
                int tpb = len - 9 - t; tpb = (tpb > 0) ? tpb : 0;
                const int tok = half ? tpb : tpf;
                lgbuf[u]  = (i < NL) ? lgp[tok * NL + i] : 0.0f;
                labbuf[u] = labp[tok];
            }
            const bool upd = (t < nup);

            // ---- gold score ----
            int prv;
            if (half) {
                const int utok = len - 1 - t;
                prv = (utok >= 1) ? labnxt : (L - 2);
            } else {
                prv = prevF;
            }
            utot += (upd && i == lab) ? lg : 0.0f;
            const float gtr = Tsh[lab * L + prv];
            btot += upd ? gtr : 0.0f;
            prevF = upd ? lab : prevF;   // only meaningful for fwd half

            const float el = (i < NL) ? __expf(lg) : 0.0f;
            const float pe = p * el;
            const float wv = half ? pe : p;   // bwd multiplies exp(logit) BEFORE matvec

            // ---- broadcast through LDS (parity double-buffer) ----
            float* pb = &pbuf[wave][half][u & 1][0];
            if (act) pb[i] = wv;
            asm volatile("s_waitcnt lgkmcnt(0)" ::: "memory");
            const float4* q = (const float4*)pb;
            const float4 q0 = q[0], q1 = q[1], q2 = q[2], q3 = q[3], q4 = q[4];

            float a0 = q0.x * coef[0];
            float a1 = q0.y * coef[1];
            float a2 = q0.z * coef[2];
            float a3 = q0.w * coef[3];
            a0 = fmaf(q1.x, coef[4],  a0);
            a1 = fmaf(q1.y, coef[5],  a1);
            a2 = fmaf(q1.z, coef[6],  a2);
            a3 = fmaf(q1.w, coef[7],  a3);
            a0 = fmaf(q2.x, coef[8],  a0);
            a1 = fmaf(q2.y, coef[9],  a1);
            a2 = fmaf(q2.z, coef[10], a2);
            a3 = fmaf(q2.w, coef[11], a3);
            a0 = fmaf(q3.x, coef[12], a0);
            a1 = fmaf(q3.y, coef[13], a1);
            a2 = fmaf(q3.z, coef[14], a2);
            a3 = fmaf(q3.w, coef[15], a3);
            a0 = fmaf(q4.x, coef[16], a0);
            a1 = fmaf(q4.y, coef[17], a1);
            a2 = fmaf(q4.z, coef[18], a2);

            const float v   = (a0 + a1) + (a2 + a3);
            const float elf = half ? 1.0f : el;  // fwd multiplies AFTER matvec
            float pn = v * elf;

            // renormalize every 4 steps (any positive scale works; track log)
            if ((t & 3) == 3) {
                float m0 = fmaxf(fmaxf(q0.x, q0.y), fmaxf(q0.z, q0.w));
                float m1 = fmaxf(fmaxf(q1.x, q1.y), fmaxf(q1.z, q1.w));
                float m2 = fmaxf(fmaxf(q2.x, q2.y), fmaxf(q2.z, q2.w));
                float m3 = fmaxf(fmaxf(q3.x, q3.y), fmaxf(q3.z, q3.w));
                float m4 = fmaxf(fmaxf(q4.x, q4.y), q4.z);
                float mx = fmaxf(fmaxf(m0, m1), fmaxf(fmaxf(m2, m3), m4));
                pn *= __frcp_rn(mx);
                if (upd) m += __logf(mx);
            }
            p = upd ? pn : p;
        }
    }

    // ---- epilogue: P = sum_j A_mid[j] * B_mid[j] ----
    const float other = __shfl_xor(p, 32);          // partner half's vector
    float prod = act ? p * other : 0.0f;
    #pragma unroll
    for (int off = 16; off >= 1; off >>= 1)
        prod += __shfl_xor(prod, off, 32);
    const float mtot = m + __shfl_xor(m, 32);       // m_fwd + m_bwd
    const float norm = mtot + __logf(prod);

    #pragma unroll
    for (int off = 16; off >= 1; off >>= 1)
        utot += __shfl_xor(utot, off, 32);
    const float ghalf = utot + btot;                // this half's gold part
    const float gold  = ghalf + __shfl_xor(ghalf, 32);

    if (wtid == 0) out[b] = gold - norm;
}

extern "C" void kernel_launch(void* const* d_in, const int* in_sizes, int n_in,
                              void* d_out, int out_size, void* d_ws, size_t ws_size,
                              hipStream_t stream)
{
    (void)n_in; (void)out_size; (void)d_ws; (void)ws_size;
    const float* logits     = (const float*)d_in[0];
    const int*   labels     = (const int*)d_in[1];
    const int*   lens       = (const int*)d_in[2];
    const float* transition = (const float*)d_in[3];
    float*       out        = (float*)d_out;
    const int B = in_sizes[2];
    crf_fwd<<<dim3(B / WPB), dim3(64 * WPB), 0, stream>>>(logits, labels, lens, transition, out);
}

// Round 4
// 137.133 us; speedup vs baseline: 1.4138x; 1.0236x over previous
//
#include <hip/hip_runtime.h>

constexpr int S   = 256;
constexpr int NL  = 17;
constexpr int L   = 19;   // start = 17, end = 18
constexpr int WPB = 2;    // waves per block

// One wave per sequence. Half 0: fwd Z <- E (el o Z), Z0 = E[:,start], tokens
// [0,mid). Half 1: bwd V <- E^T (el o V), V0 = E[end,:], tokens (mid,len-1]
// walking down, plus a final elementwise el_mid. Combine P = sum Z*(el_mid o V).
// Gold path score computed post-loop by all 64 lanes. Probability domain,
// per-4-step max renorm, lgkmcnt-only fences, depth-8 prefetch.
__global__ __launch_bounds__(64 * WPB)
void crf_fwd(const float* __restrict__ logits,
             const int*   __restrict__ labels,
             const int*   __restrict__ lens,
             const float* __restrict__ transition,
             float* __restrict__ out, int totalElemM1)
{
    __shared__ float Tsh[L * L];
    __shared__ __align__(16) float pbuf[WPB][2][2][32];  // [wave][half][parity]

    const int tid  = threadIdx.x;
    const int wave = tid >> 6;
    const int wtid = tid & 63;
    const int half = wtid >> 5;   // 0 = fwd, 1 = bwd
    const int lane = wtid & 31;
    const int b    = blockIdx.x * WPB + wave;

    for (int k = tid; k < L * L; k += 64 * WPB) Tsh[k] = transition[k];
    __syncthreads();   // once; wave-local fences afterwards

    const int  i    = lane;
    const bool act  = (i < L);
    const bool emit = (i < NL);
    const int  ic   = act ? i : 0;

    // fwd lane i: row i of E ; bwd lane i: column i of E
    float coef[L];
    #pragma unroll
    for (int j = 0; j < L; ++j)
        coef[j] = __expf(half ? Tsh[j * L + ic] : Tsh[ic * L + j]);

    const int len = lens[b];
    const int mid = len >> 1;            // fwd full steps
    const int nb  = len - 1 - mid;       // bwd full steps (mid-1 or mid)
    const int nup = half ? nb : mid;
    const int nsteps = (mid + 7) & ~7;   // mid >= nb always

    const int seqbase = b * (S * NL);    // element index of this seq

    // init state vector
    float p = act ? __expf(half ? Tsh[(L - 1) * L + ic]     // E[end, i]
                                : Tsh[ic * L + (L - 2)])    // E[i, start]
                  : 0.0f;
    float m = 0.0f;

    // ---- depth-8 prefetch: 32-bit byte offsets, per-lane clamps ----
    const char* lgbase = (const char*)logits;
    const int capHiF = 4 * min(seqbase + (S - 1) * NL + i, totalElemM1);
    const int capHi  = half ? 0x7ffffffc : capHiF;
    const int capLo  = half ? 4 * (seqbase + i) : 0;
    const int stride = half ? -(8 * NL * 4) : (8 * NL * 4);

    int   off[8];
    float lgbuf[8];
    #pragma unroll
    for (int u = 0; u < 8; ++u) {
        int tok = half ? (len - 1 - u) : u;
        tok = tok > 0 ? tok : 0;
        int o = 4 * (seqbase + tok * NL + i);
        o = min(o, capHiF);
        off[u] = o;
        lgbuf[u] = *(const float*)(lgbase + o);
    }

    for (int tb = 0; tb < nsteps; tb += 8) {
        #pragma unroll
        for (int u = 0; u < 8; ++u) {
            const int   t  = tb + u;
            const float lg = lgbuf[u];
            // advance pipeline
            int o = off[u] + stride;
            o = max(o, capLo);
            o = min(o, capHi);
            off[u] = o;
            lgbuf[u] = *(const float*)(lgbase + o);

            const bool upd = (t < nup);

            const float el = emit ? __expf(lg) : 0.0f;
            const float pe = p * el;

            float* pb = &pbuf[wave][half][u & 1][0];
            pb[i] = pe;                                   // all 32 lanes write
            asm volatile("s_waitcnt lgkmcnt(0)" ::: "memory");
            const float4* q = (const float4*)pb;
            const float4 q0 = q[0], q1 = q[1], q2 = q[2], q3 = q[3], q4 = q[4];

            float a0 = q0.x * coef[0];
            float a1 = q0.y * coef[1];
            float a2 = q0.z * coef[2];
            float a3 = q0.w * coef[3];
            a0 = fmaf(q1.x, coef[4],  a0);
            a1 = fmaf(q1.y, coef[5],  a1);
            a2 = fmaf(q1.z, coef[6],  a2);
            a3 = fmaf(q1.w, coef[7],  a3);
            a0 = fmaf(q2.x, coef[8],  a0);
            a1 = fmaf(q2.y, coef[9],  a1);
            a2 = fmaf(q2.z, coef[10], a2);
            a3 = fmaf(q2.w, coef[11], a3);
            a0 = fmaf(q3.x, coef[12], a0);
            a1 = fmaf(q3.y, coef[13], a1);
            a2 = fmaf(q3.z, coef[14], a2);
            a3 = fmaf(q3.w, coef[15], a3);
            a0 = fmaf(q4.x, coef[16], a0);
            a1 = fmaf(q4.y, coef[17], a1);
            a2 = fmaf(q4.z, coef[18], a2);

            float pn = (a0 + a1) + (a2 + a3);

            if ((u & 3) == 3) {   // renorm every 4 steps
                float m0 = fmaxf(fmaxf(q0.x, q0.y), fmaxf(q0.z, q0.w));
                float m1 = fmaxf(fmaxf(q1.x, q1.y), fmaxf(q1.z, q1.w));
                float m2 = fmaxf(fmaxf(q2.x, q2.y), fmaxf(q2.z, q2.w));
                float m3 = fmaxf(fmaxf(q3.x, q3.y), fmaxf(q3.z, q3.w));
                float m4 = fmaxf(fmaxf(q4.x, q4.y), q4.z);
                float mx = fmaxf(fmaxf(m0, m1), fmaxf(fmaxf(m2, m3), m4));
                pn *= __frcp_rn(mx);
                m += upd ? __logf(mx) : 0.0f;
            }
            p = upd ? pn : p;
        }
    }

    // ---- bwd leftover: multiply by el of token `mid` (no matvec) ----
    {
        float lgf = 0.0f;
        if (half && emit) lgf = logits[(size_t)(seqbase + mid * NL + i)];
        if (half) p = emit ? p * __expf(lgf) : 0.0f;
    }

    // ---- combine: P = sum_i Z_i * Vp_i ----
    const float other = __shfl_xor(p, 32);
    float prod = act ? p * other : 0.0f;
    #pragma unroll
    for (int o = 16; o >= 1; o >>= 1) prod += __shfl_xor(prod, o, 32);
    const float mtot = m + __shfl_xor(m, 32);
    const float norm = mtot + __logf(prod);

    // ---- gold phase: all 64 lanes sweep tokens ----
    const int* labp = labels + b * S;
    float gsum = 0.0f;
    for (int c = 0; c < len; c += 64) {
        const int tok = c + wtid;
        if (tok < len) {
            const int lab = labp[tok];
            const int prv = (tok == 0) ? (L - 2) : labp[tok - 1];
            gsum += logits[(size_t)(seqbase + tok * NL + lab)] + Tsh[lab * L + prv];
        }
    }
    #pragma unroll
    for (int o = 32; o >= 1; o >>= 1) gsum += __shfl_xor(gsum, o);
    const float gold = gsum + Tsh[(L - 1) * L + labp[len - 1]];

    if (wtid == 0) out[b] = gold - norm;
}

extern "C" void kernel_launch(void* const* d_in, const int* in_sizes, int n_in,
                              void* d_out, int out_size, void* d_ws, size_t ws_size,
                              hipStream_t stream)
{
    (void)n_in; (void)out_size; (void)d_ws; (void)ws_size;
    const float* logits     = (const float*)d_in[0];
    const int*   labels     = (const int*)d_in[1];
    const int*   lens       = (const int*)d_in[2];
    const float* transition = (const float*)d_in[3];
    float*       out        = (float*)d_out;
    const int B = in_sizes[2];
    const int totalElemM1 = B * S * NL - 1;
    crf_fwd<<<dim3(B / WPB), dim3(64 * WPB), 0, stream>>>(
        logits, labels, lens, transition, out, totalElemM1);
}

// Round 5
// 136.224 us; speedup vs baseline: 1.4233x; 1.0067x over previous
//
#include <hip/hip_runtime.h>

constexpr int S   = 256;
constexpr int NL  = 17;
constexpr int L   = 19;   // start = 17, end = 18
constexpr int WPB = 2;    // waves per block

// One wave per sequence. Half 0: fwd Z <- E (el o Z), Z0 = E[:,start], tokens
// [0,mid). Half 1: bwd V <- E^T (el o V), V0 = E[end,:], tokens (mid,len-1]
// walking down, plus a final elementwise el_mid. Combine P = sum Z*(el_mid o V).
// Gold path score computed post-loop by all 64 lanes. Probability domain,
// per-4-step max renorm, depth-8 prefetch.
// NOTE: no s_waitcnt between ds_write and ds_read — DS ops from one wave are
// processed in order by the LDS pipe; only a compiler barrier pins the order.
// The compiler still inserts the lgkmcnt wait before the FMAs use read data.
__global__ __launch_bounds__(64 * WPB)
void crf_fwd(const float* __restrict__ logits,
             const int*   __restrict__ labels,
             const int*   __restrict__ lens,
             const float* __restrict__ transition,
             float* __restrict__ out, int totalElemM1)
{
    __shared__ float Tsh[L * L];
    __shared__ __align__(16) float pbuf[WPB][2][2][32];  // [wave][half][parity]

    const int tid  = threadIdx.x;
    const int wave = tid >> 6;
    const int wtid = tid & 63;
    const int half = wtid >> 5;   // 0 = fwd, 1 = bwd
    const int lane = wtid & 31;
    const int b    = blockIdx.x * WPB + wave;

    for (int k = tid; k < L * L; k += 64 * WPB) Tsh[k] = transition[k];
    __syncthreads();   // once; nothing cross-wave afterwards until epilogue

    const int  i    = lane;
    const bool act  = (i < L);
    const bool emit = (i < NL);
    const int  ic   = act ? i : 0;

    // fwd lane i: row i of E ; bwd lane i: column i of E
    float coef[L];
    #pragma unroll
    for (int j = 0; j < L; ++j)
        coef[j] = __expf(half ? Tsh[j * L + ic] : Tsh[ic * L + j]);

    const int len = lens[b];
    const int mid = len >> 1;            // fwd full steps
    const int nb  = len - 1 - mid;       // bwd full steps (mid-1 or mid)
    const int nup = half ? nb : mid;
    const int nsteps = (mid + 7) & ~7;   // mid >= nb always

    const int seqbase = b * (S * NL);    // element index of this seq

    // init state vector
    float p = act ? __expf(half ? Tsh[(L - 1) * L + ic]     // E[end, i]
                                : Tsh[ic * L + (L - 2)])    // E[i, start]
                  : 0.0f;
    float m = 0.0f;

    // ---- depth-8 prefetch: 32-bit byte offsets, per-lane clamps ----
    const char* lgbase = (const char*)logits;
    const int capHiF = 4 * min(seqbase + (S - 1) * NL + i, totalElemM1);
    const int capHi  = half ? 0x7ffffffc : capHiF;
    const int capLo  = half ? 4 * (seqbase + i) : 0;
    const int stride = half ? -(8 * NL * 4) : (8 * NL * 4);

    int   off[8];
    float lgbuf[8];
    #pragma unroll
    for (int u = 0; u < 8; ++u) {
        int tok = half ? (len - 1 - u) : u;
        tok = tok > 0 ? tok : 0;
        int o = 4 * (seqbase + tok * NL + i);
        o = min(o, capHiF);
        off[u] = o;
        lgbuf[u] = *(const float*)(lgbase + o);
    }

    for (int tb = 0; tb < nsteps; tb += 8) {
        #pragma unroll
        for (int u = 0; u < 8; ++u) {
            const int   t  = tb + u;
            const float lg = lgbuf[u];
            // advance pipeline
            int o = off[u] + stride;
            o = max(o, capLo);
            o = min(o, capHi);
            off[u] = o;
            lgbuf[u] = *(const float*)(lgbase + o);

            const bool upd = (t < nup);

            const float el = emit ? __expf(lg) : 0.0f;
            const float pe = p * el;

            float* pb = &pbuf[wave][half][u & 1][0];
            pb[i] = pe;                                   // all 32 lanes write
            // compiler-only barrier: keeps the reads after the write in program
            // order; hardware DS pipe is in-order per wave, so no s_waitcnt here.
            asm volatile("" ::: "memory");
            const float4* q = (const float4*)pb;
            const float4 q0 = q[0], q1 = q[1], q2 = q[2], q3 = q[3], q4 = q[4];

            float a0 = q0.x * coef[0];
            float a1 = q0.y * coef[1];
            float a2 = q0.z * coef[2];
            float a3 = q0.w * coef[3];
            a0 = fmaf(q1.x, coef[4],  a0);
            a1 = fmaf(q1.y, coef[5],  a1);
            a2 = fmaf(q1.z, coef[6],  a2);
            a3 = fmaf(q1.w, coef[7],  a3);
            a0 = fmaf(q2.x, coef[8],  a0);
            a1 = fmaf(q2.y, coef[9],  a1);
            a2 = fmaf(q2.z, coef[10], a2);
            a3 = fmaf(q2.w, coef[11], a3);
            a0 = fmaf(q3.x, coef[12], a0);
            a1 = fmaf(q3.y, coef[13], a1);
            a2 = fmaf(q3.z, coef[14], a2);
            a3 = fmaf(q3.w, coef[15], a3);
            a0 = fmaf(q4.x, coef[16], a0);
            a1 = fmaf(q4.y, coef[17], a1);
            a2 = fmaf(q4.z, coef[18], a2);

            float pn = (a0 + a1) + (a2 + a3);

            if ((u & 3) == 3) {   // renorm every 4 steps
                float m0 = fmaxf(fmaxf(q0.x, q0.y), fmaxf(q0.z, q0.w));
                float m1 = fmaxf(fmaxf(q1.x, q1.y), fmaxf(q1.z, q1.w));
                float m2 = fmaxf(fmaxf(q2.x, q2.y), fmaxf(q2.z, q2.w));
                float m3 = fmaxf(fmaxf(q3.x, q3.y), fmaxf(q3.z, q3.w));
                float m4 = fmaxf(fmaxf(q4.x, q4.y), q4.z);
                float mx = fmaxf(fmaxf(m0, m1), fmaxf(fmaxf(m2, m3), m4));
                pn *= __frcp_rn(mx);
                m += upd ? __logf(mx) : 0.0f;
            }
            p = upd ? pn : p;
        }
    }

    // ---- bwd leftover: multiply by el of token `mid` (no matvec) ----
    {
        float lgf = 0.0f;
        if (half && emit) lgf = logits[(size_t)(seqbase + mid * NL + i)];
        if (half) p = emit ? p * __expf(lgf) : 0.0f;
    }

    // ---- combine: P = sum_i Z_i * Vp_i ----
    const float other = __shfl_xor(p, 32);
    float prod = act ? p * other : 0.0f;
    #pragma unroll
    for (int o = 16; o >= 1; o >>= 1) prod += __shfl_xor(prod, o, 32);
    const float mtot = m + __shfl_xor(m, 32);
    const float norm = mtot + __logf(prod);

    // ---- gold phase: all 64 lanes sweep tokens ----
    const int* labp = labels + b * S;
    float gsum = 0.0f;
    for (int c = 0; c < len; c += 64) {
        const int tok = c + wtid;
        if (tok < len) {
            const int lab = labp[tok];
            const int prv = (tok == 0) ? (L - 2) : labp[tok - 1];
            gsum += logits[(size_t)(seqbase + tok * NL + lab)] + Tsh[lab * L + prv];
        }
    }
    #pragma unroll
    for (int o = 32; o >= 1; o >>= 1) gsum += __shfl_xor(gsum, o);
    const float gold = gsum + Tsh[(L - 1) * L + labp[len - 1]];

    if (wtid == 0) out[b] = gold - norm;
}

extern "C" void kernel_launch(void* const* d_in, const int* in_sizes, int n_in,
                              void* d_out, int out_size, void* d_ws, size_t ws_size,
                              hipStream_t stream)
{
    (void)n_in; (void)out_size; (void)d_ws; (void)ws_size;
    const float* logits     = (const float*)d_in[0];
    const int*   labels     = (const int*)d_in[1];
    const int*   lens       = (const int*)d_in[2];
    const float* transition = (const float*)d_in[3];
    float*       out        = (float*)d_out;
    const int B = in_sizes[2];
    const int totalElemM1 = B * S * NL - 1;
    crf_fwd<<<dim3(B / WPB), dim3(64 * WPB), 0, stream>>>(
        logits, labels, lens, transition, out, totalElemM1);
}